// Round 1
// baseline (334.627 us; speedup 1.0000x reference)
//
#include <hip/hip_runtime.h>
#include <math.h>

typedef unsigned short u16;
typedef short bf16x8 __attribute__((ext_vector_type(8)));
typedef u16 u16x2 __attribute__((ext_vector_type(2)));
typedef u16 u16x4 __attribute__((ext_vector_type(4)));
typedef u16 u16x8 __attribute__((ext_vector_type(8)));
typedef float f32x2 __attribute__((ext_vector_type(2)));
typedef float f32x4 __attribute__((ext_vector_type(4)));

typedef __attribute__((address_space(1))) const void gvoid_t;
typedef __attribute__((address_space(3))) void lvoid_t;

__device__ __forceinline__ u16 f2bf(float f) {
  union { float f; unsigned u; } v; v.f = f;
  unsigned r = v.u + 0x7fffu + ((v.u >> 16) & 1u);
  return (u16)(r >> 16);
}
__device__ __forceinline__ float bf2f(u16 h) {
  union { unsigned u; float f; } v; v.u = ((unsigned)h) << 16;
  return v.f;
}
__device__ __forceinline__ f32x4 mfma16(bf16x8 a, bf16x8 b, f32x4 c) {
  return __builtin_amdgcn_mfma_f32_16x16x32_bf16(a, b, c, 0, 0, 0);
}
__device__ __forceinline__ void gload_lds16(const void* g, void* l) {
  __builtin_amdgcn_global_load_lds((gvoid_t*)g, (lvoid_t*)l, 16, 0, 0);
}

// ---------------- fp32 -> bf16 conversion ----------------
__global__ __launch_bounds__(256) void cvt_bf16_kernel(const float* __restrict__ in,
                                                       u16* __restrict__ out, int n4) {
  int i = blockIdx.x * 256 + threadIdx.x;
  if (i >= n4) return;
  f32x4 v = *(const f32x4*)(in + (size_t)i * 4);
  u16x4 o;
  o[0] = f2bf(v[0]); o[1] = f2bf(v[1]); o[2] = f2bf(v[2]); o[3] = f2bf(v[3]);
  *(u16x4*)(out + (size_t)i * 4) = o;
}

// ---------------- RoPE cos/sin tables [T][64] ----------------
__global__ __launch_bounds__(256) void rope_tab_kernel(float* __restrict__ ct,
                                                       float* __restrict__ st) {
  int i = blockIdx.x * 256 + threadIdx.x;   // T*64 = 131072
  int t = i >> 6, j = i & 63;
  float inv = powf(10000.f, -(float)j * (1.0f / 64.0f));
  float ang = (float)t * inv;
  ct[i] = cosf(ang);
  st[i] = sinf(ang);
}

// ---------------- GEMM: C[M,N] = A[M,K] * B[N,K]^T (bf16 in, m97 structure) ----------------
template <int OUTF32>
__global__ __launch_bounds__(256) void gemm_bt_kernel(
    const u16* __restrict__ A, const u16* __restrict__ B, void* __restrict__ C,
    const float* __restrict__ bias, int M, int N, int K, int ntn) {
  constexpr int BK = 64;
  __shared__ u16 Alds[128 * BK];
  __shared__ u16 Blds[128 * BK];
  int bid = blockIdx.x;
  int per_g = 8 * ntn;
  int g = bid / per_g, ing = bid % per_g;
  int bm = g * 8 + (ing & 7), bn = ing >> 3;     // group-of-8 M supertile for L2 reuse
  size_t m0 = (size_t)bm * 128, n0 = (size_t)bn * 128;
  int tid = threadIdx.x, wid = tid >> 6, lane = tid & 63;
  int wr = wid >> 1, wc = wid & 1, l15 = lane & 15, l4 = lane >> 4;
  int srow = lane >> 3, sch = lane & 7;

  f32x4 acc[4][4];
#pragma unroll
  for (int a = 0; a < 4; a++)
#pragma unroll
    for (int b2 = 0; b2 < 4; b2++) acc[a][b2] = f32x4{0.f, 0.f, 0.f, 0.f};

  int nk = K >> 6;
  for (int kt = 0; kt < nk; ++kt) {
    int k0 = kt << 6;
    __syncthreads();
    const u16* ga = A + (m0 + 32 * wid + srow) * K + k0 + sch * 8;
    const u16* gb = B + (n0 + 32 * wid + srow) * K + k0 + sch * 8;
#pragma unroll
    for (int c = 0; c < 4; c++) {
      gload_lds16(ga + (size_t)(8 * c) * K, &Alds[(32 * wid + 8 * c) * BK]);
      gload_lds16(gb + (size_t)(8 * c) * K, &Blds[(32 * wid + 8 * c) * BK]);
    }
    __syncthreads();
#pragma unroll
    for (int kk = 0; kk < 2; kk++) {
      bf16x8 af[4], bfr[4];
#pragma unroll
      for (int mi = 0; mi < 4; mi++)
        af[mi] = *(const bf16x8*)&Alds[(64 * wr + 16 * mi + l15) * BK + kk * 32 + 8 * l4];
#pragma unroll
      for (int ni = 0; ni < 4; ni++)
        bfr[ni] = *(const bf16x8*)&Blds[(64 * wc + 16 * ni + l15) * BK + kk * 32 + 8 * l4];
#pragma unroll
      for (int mi = 0; mi < 4; mi++)
#pragma unroll
        for (int ni = 0; ni < 4; ni++)
          acc[mi][ni] = mfma16(af[mi], bfr[ni], acc[mi][ni]);
    }
  }
#pragma unroll
  for (int mi = 0; mi < 4; mi++) {
#pragma unroll
    for (int ni = 0; ni < 4; ni++) {
      size_t row = m0 + 64 * wr + 16 * mi + 4 * l4;
      size_t col = n0 + 64 * wc + 16 * ni + l15;
#pragma unroll
      for (int i = 0; i < 4; i++) {
        float v = acc[mi][ni][i];
        if constexpr (OUTF32) {
          ((float*)C)[(row + i) * N + col] = v + bias[col];
        } else {
          ((u16*)C)[(row + i) * N + col] = f2bf(v);
        }
      }
    }
  }
}

// ---------------- transform: RMSNorm + RoPE + v-mix, layouts for attention ----------------
__global__ __launch_bounds__(256) void transform_kernel(
    const u16* __restrict__ qkv, const float* __restrict__ ve,
    const float* __restrict__ lam, const float* __restrict__ ct,
    const float* __restrict__ st, u16* __restrict__ qn, u16* __restrict__ kn,
    u16* __restrict__ vt) {
  constexpr int T = 2048, HD = 128;
  __shared__ u16 vtile[64][132];
  int tt = blockIdx.x, bh = blockIdx.y;
  int b = bh >> 3, h = bh & 7;
  int tid = threadIdx.x, wid = tid >> 6, lane = tid & 63;
  float l0 = lam[0], l1 = lam[1];
  int d0 = 2 * lane;
  float sgn = (lane < 32) ? -1.f : 1.f;
#pragma unroll 1
  for (int j = 0; j < 16; ++j) {
    int tl = wid * 16 + j;
    int t = tt * 64 + tl;
    size_t base = ((size_t)(b * T + t)) * 3072 + h * HD + d0;
    u16x2 qraw = *(const u16x2*)(qkv + base);
    u16x2 kraw = *(const u16x2*)(qkv + base + 1024);
    u16x2 vraw = *(const u16x2*)(qkv + base + 2048);
    f32x2 vef = *(const f32x2*)(ve + ((size_t)(b * T + t)) * 1024 + h * HD + d0);
    float q0 = bf2f(qraw[0]), q1 = bf2f(qraw[1]);
    float k0 = bf2f(kraw[0]), k1 = bf2f(kraw[1]);
    float sq = q0 * q0 + q1 * q1, sk = k0 * k0 + k1 * k1;
#pragma unroll
    for (int m = 1; m < 64; m <<= 1) {
      sq += __shfl_xor(sq, m);
      sk += __shfl_xor(sk, m);
    }
    float qs = rsqrtf(sq * (1.f / 128.f) + 1.1920929e-7f);
    float ks = rsqrtf(sk * (1.f / 128.f) + 1.1920929e-7f);
    q0 *= qs; q1 *= qs; k0 *= ks; k1 *= ks;
    int jj = d0 & 63;
    f32x2 c2 = *(const f32x2*)(ct + t * 64 + jj);
    f32x2 s2 = *(const f32x2*)(st + t * 64 + jj);
    float q0p = __shfl_xor(q0, 32), q1p = __shfl_xor(q1, 32);
    float k0p = __shfl_xor(k0, 32), k1p = __shfl_xor(k1, 32);
    u16x2 oq, ok;
    oq[0] = f2bf(q0 * c2[0] + sgn * q0p * s2[0]);
    oq[1] = f2bf(q1 * c2[1] + sgn * q1p * s2[1]);
    ok[0] = f2bf(k0 * c2[0] + sgn * k0p * s2[0]);
    ok[1] = f2bf(k1 * c2[1] + sgn * k1p * s2[1]);
    size_t orow = ((size_t)bh * T + t) * HD + d0;
    *(u16x2*)(qn + orow) = oq;
    *(u16x2*)(kn + orow) = ok;
    vtile[tl][d0] = f2bf(l0 * bf2f(vraw[0]) + l1 * vef[0]);
    vtile[tl][d0 + 1] = f2bf(l0 * bf2f(vraw[1]) + l1 * vef[1]);
  }
  __syncthreads();
  // write V transposed: vt[bh][d][t]
#pragma unroll
  for (int it = 0; it < 4; ++it) {
    int ci = it * 256 + tid;       // 128 d-rows x 8 chunks of 8 t
    int d = ci >> 3, c8 = ci & 7;
    u16x8 o;
#pragma unroll
    for (int u = 0; u < 8; u++) o[u] = vtile[c8 * 8 + u][d];
    *(u16x8*)(vt + ((size_t)bh * HD + d) * T + tt * 64 + c8 * 8) = o;
  }
}

// ---------------- causal flash attention ----------------
__global__ __launch_bounds__(256) void attn_kernel(const u16* __restrict__ Qn,
                                                   const u16* __restrict__ Kn,
                                                   const u16* __restrict__ Vt,
                                                   u16* __restrict__ Y) {
  constexpr int T = 2048, HD = 128;
  __shared__ u16 Klds[64 * 128];      // [krow][d], XOR-swizzled
  __shared__ u16 Vlds[128 * 64];      // [d][kcol] (V^T), XOR-swizzled
  __shared__ u16 Plds[4][16 * 64];    // per-wave P tile, XOR-swizzled
  int qt = blockIdx.x, bh = blockIdx.y;
  int b = bh >> 3, h = bh & 7;
  int tid = threadIdx.x, wid = tid >> 6, lane = tid & 63;
  int l15 = lane & 15, l4 = lane >> 4;
  const u16* Qb = Qn + (size_t)bh * T * HD;
  const u16* Kb = Kn + (size_t)bh * T * HD;
  const u16* Vb = Vt + (size_t)bh * HD * T;

  bf16x8 qf[4];
  {
    const u16* qr = Qb + (size_t)(qt * 64 + wid * 16 + l15) * HD + 8 * l4;
#pragma unroll
    for (int kg = 0; kg < 4; kg++) qf[kg] = *(const bf16x8*)(qr + kg * 32);
  }

  f32x4 acc[8];
#pragma unroll
  for (int n = 0; n < 8; n++) acc[n] = f32x4{0.f, 0.f, 0.f, 0.f};
  float mrow[4] = {-1e30f, -1e30f, -1e30f, -1e30f};
  float lrow[4] = {0.f, 0.f, 0.f, 0.f};
  int qrow0 = qt * 64 + wid * 16;

  for (int kt = 0; kt <= qt; ++kt) {
    __syncthreads();
    // stage K tile [64][128] and V^T tile [128][64], both swizzled
#pragma unroll
    for (int it = 0; it < 4; ++it) {
      int ci = it * 256 + tid;
      int r = ci >> 4, ch = ci & 15;
      u16x8 kv = *(const u16x8*)(Kb + (size_t)(kt * 64 + r) * HD + ch * 8);
      *(u16x8*)((char*)Klds + ((r * 256 + ch * 16) ^ ((r & 7) << 4))) = kv;
      int d = ci >> 3, c2 = ci & 7;
      u16x8 vv = *(const u16x8*)(Vb + (size_t)d * T + kt * 64 + c2 * 8);
      *(u16x8*)((char*)Vlds + ((d * 128 + c2 * 16) ^ ((d & 7) << 4))) = vv;
    }
    __syncthreads();

    // S = Q K^T for this tile (per-wave 16x64)
    f32x4 s[4];
#pragma unroll
    for (int n = 0; n < 4; n++) s[n] = f32x4{0.f, 0.f, 0.f, 0.f};
#pragma unroll
    for (int kg = 0; kg < 4; kg++) {
#pragma unroll
      for (int n = 0; n < 4; n++) {
        int r = n * 16 + l15;
        bf16x8 kf = *(const bf16x8*)((char*)Klds +
                      ((r * 256 + (kg * 64 + 16 * l4)) ^ ((r & 7) << 4)));
        s[n] = mfma16(qf[kg], kf, s[n]);
      }
    }
    bool edge = (kt == qt);
    float pm[4] = {-1e30f, -1e30f, -1e30f, -1e30f};
#pragma unroll
    for (int n = 0; n < 4; n++) {
      int colg = kt * 64 + n * 16 + l15;
#pragma unroll
      for (int i = 0; i < 4; i++) {
        float sv = s[n][i] * 0.12f;
        if (edge && (colg > qrow0 + 4 * l4 + i)) sv = -1e30f;
        s[n][i] = sv;
        pm[i] = fmaxf(pm[i], sv);
      }
    }
#pragma unroll
    for (int off = 1; off < 16; off <<= 1)
#pragma unroll
      for (int i = 0; i < 4; i++) pm[i] = fmaxf(pm[i], __shfl_xor(pm[i], off));
    float alpha[4], ps[4];
#pragma unroll
    for (int i = 0; i < 4; i++) {
      float mn = fmaxf(mrow[i], pm[i]);
      alpha[i] = __expf(mrow[i] - mn);
      mrow[i] = mn;
      ps[i] = 0.f;
    }
    // P = exp(S - m) -> bf16 -> per-wave LDS (swizzled)
#pragma unroll
    for (int n = 0; n < 4; n++) {
#pragma unroll
      for (int i = 0; i < 4; i++) {
        float p = __expf(s[n][i] - mrow[i]);
        ps[i] += p;
        int pr = 4 * l4 + i;
        *(u16*)((char*)&Plds[wid][0] +
                ((pr * 128 + (n * 16 + l15) * 2) ^ ((pr & 7) << 4))) = f2bf(p);
      }
    }
#pragma unroll
    for (int off = 1; off < 16; off <<= 1)
#pragma unroll
      for (int i = 0; i < 4; i++) ps[i] += __shfl_xor(ps[i], off);
#pragma unroll
    for (int i = 0; i < 4; i++) lrow[i] = lrow[i] * alpha[i] + ps[i];
#pragma unroll
    for (int n = 0; n < 8; n++)
#pragma unroll
      for (int i = 0; i < 4; i++) acc[n][i] *= alpha[i];
    // acc += P * V
#pragma unroll
    for (int kk = 0; kk < 2; kk++) {
      bf16x8 pf = *(const bf16x8*)((char*)&Plds[wid][0] +
                    ((l15 * 128 + kk * 64 + 16 * l4) ^ ((l15 & 7) << 4)));
#pragma unroll
      for (int n = 0; n < 8; n++) {
        int vr = n * 16 + l15;
        bf16x8 vf = *(const bf16x8*)((char*)Vlds +
                      ((vr * 128 + kk * 64 + 16 * l4) ^ ((vr & 7) << 4)));
        acc[n] = mfma16(pf, vf, acc[n]);
      }
    }
  }
  // epilogue: Y[b*T + row][h*128 + col] = acc / l
#pragma unroll
  for (int i = 0; i < 4; i++) {
    float inv = 1.f / lrow[i];
    size_t row = (size_t)b * T + qrow0 + 4 * l4 + i;
#pragma unroll
    for (int n = 0; n < 8; n++) {
      Y[row * 1024 + h * 128 + n * 16 + l15] = f2bf(acc[n][i] * inv);
    }
  }
}

// ---------------- launch ----------------
extern "C" void kernel_launch(void* const* d_in, const int* in_sizes, int n_in,
                              void* d_out, int out_size, void* d_ws, size_t ws_size,
                              hipStream_t stream) {
  (void)in_sizes; (void)n_in; (void)out_size; (void)ws_size;
  const float* x = (const float*)d_in[0];
  const float* ve = (const float*)d_in[1];
  const float* qkvw = (const float*)d_in[2];
  const float* lam = (const float*)d_in[3];
  const float* cpw = (const float*)d_in[4];
  const float* cpb = (const float*)d_in[5];
  float* out = (float*)d_out;
  char* ws = (char*)d_ws;

  u16* xb   = (u16*)(ws + 0);           // 16 MB  (aliased by y after GEMM1)
  u16* wqkv = (u16*)(ws + 16777216);    // 6 MB
  u16* wp   = (u16*)(ws + 23068672);    // 2 MB
  u16* qkv  = (u16*)(ws + 25165824);    // 48 MB
  u16* qn   = (u16*)(ws + 75497472);    // 16 MB
  u16* kn   = (u16*)(ws + 92274688);    // 16 MB
  u16* vt   = (u16*)(ws + 109051904);   // 16 MB
  float* ctab = (float*)(ws + 125829120);  // 0.5 MB
  float* stab = (float*)(ws + 126353408);  // 0.5 MB
  u16* y = xb;                          // alias: xb dead after GEMM1

  rope_tab_kernel<<<512, 256, 0, stream>>>(ctab, stab);
  cvt_bf16_kernel<<<8192, 256, 0, stream>>>(x, xb, 2097152);
  cvt_bf16_kernel<<<3072, 256, 0, stream>>>(qkvw, wqkv, 786432);
  cvt_bf16_kernel<<<1024, 256, 0, stream>>>(cpw, wp, 262144);
  gemm_bt_kernel<0><<<1536, 256, 0, stream>>>(xb, wqkv, qkv, nullptr, 8192, 3072, 1024, 24);
  transform_kernel<<<dim3(32, 32), 256, 0, stream>>>(qkv, ve, lam, ctab, stab, qn, kn, vt);
  attn_kernel<<<dim3(32, 32), 256, 0, stream>>>(qn, kn, vt, y);
  gemm_bt_kernel<1><<<512, 256, 0, stream>>>(y, wp, out, cpb, 8192, 1024, 1024, 8);
}

// Round 2
// 226.697 us; speedup vs baseline: 1.4761x; 1.4761x over previous
//
#include <hip/hip_runtime.h>
#include <math.h>

typedef unsigned short u16;
typedef short bf16x8 __attribute__((ext_vector_type(8)));
typedef u16 u16x2 __attribute__((ext_vector_type(2)));
typedef u16 u16x4 __attribute__((ext_vector_type(4)));
typedef u16 u16x8 __attribute__((ext_vector_type(8)));
typedef float f32x2 __attribute__((ext_vector_type(2)));
typedef float f32x4 __attribute__((ext_vector_type(4)));
typedef float f32x16 __attribute__((ext_vector_type(16)));

typedef __attribute__((address_space(1))) const void gvoid_t;
typedef __attribute__((address_space(3))) void lvoid_t;

__device__ __forceinline__ u16 f2bf(float f) {
  union { float f; unsigned u; } v; v.f = f;
  unsigned r = v.u + 0x7fffu + ((v.u >> 16) & 1u);
  return (u16)(r >> 16);
}
__device__ __forceinline__ float bf2f(u16 h) {
  union { unsigned u; float f; } v; v.u = ((unsigned)h) << 16;
  return v.f;
}
__device__ __forceinline__ f32x4 mfma16(bf16x8 a, bf16x8 b, f32x4 c) {
  return __builtin_amdgcn_mfma_f32_16x16x32_bf16(a, b, c, 0, 0, 0);
}
__device__ __forceinline__ f32x16 mfma32(bf16x8 a, bf16x8 b, f32x16 c) {
  return __builtin_amdgcn_mfma_f32_32x32x16_bf16(a, b, c, 0, 0, 0);
}
__device__ __forceinline__ void gload_lds16(const void* g, void* l) {
  __builtin_amdgcn_global_load_lds((gvoid_t*)g, (lvoid_t*)l, 16, 0, 0);
}
__device__ __forceinline__ unsigned cvtpk_bf16(float lo, float hi) {
  unsigned r;
  asm("v_cvt_pk_bf16_f32 %0, %1, %2" : "=v"(r) : "v"(lo), "v"(hi));
  return r;
}
// v_permlane32_swap_b32: a.hi <-> b.lo  =>  a = {a.lo, b.lo}, b = {a.hi, b.hi}
__device__ __forceinline__ void pswap32(unsigned& a, unsigned& b) {
  asm("v_permlane32_swap_b32 %0, %1" : "+v"(a), "+v"(b));
}

// ---------------- fp32 -> bf16 conversion ----------------
__global__ __launch_bounds__(256) void cvt_bf16_kernel(const float* __restrict__ in,
                                                       u16* __restrict__ out, int n4) {
  int i = blockIdx.x * 256 + threadIdx.x;
  if (i >= n4) return;
  f32x4 v = *(const f32x4*)(in + (size_t)i * 4);
  u16x4 o;
  o[0] = f2bf(v[0]); o[1] = f2bf(v[1]); o[2] = f2bf(v[2]); o[3] = f2bf(v[3]);
  *(u16x4*)(out + (size_t)i * 4) = o;
}

// ---------------- RoPE cos/sin tables [T][64] ----------------
__global__ __launch_bounds__(256) void rope_tab_kernel(float* __restrict__ ct,
                                                       float* __restrict__ st) {
  int i = blockIdx.x * 256 + threadIdx.x;   // T*64 = 131072
  int t = i >> 6, j = i & 63;
  float inv = powf(10000.f, -(float)j * (1.0f / 64.0f));
  float ang = (float)t * inv;
  ct[i] = cosf(ang);
  st[i] = sinf(ang);
}

// ---------------- GEMM: C[M,N] = A[M,K] * B[N,K]^T (bf16 in, m97 structure) ----------------
template <int OUTF32>
__global__ __launch_bounds__(256) void gemm_bt_kernel(
    const u16* __restrict__ A, const u16* __restrict__ B, void* __restrict__ C,
    const float* __restrict__ bias, int M, int N, int K, int ntn) {
  constexpr int BK = 64;
  __shared__ u16 Alds[128 * BK];
  __shared__ u16 Blds[128 * BK];
  int bid = blockIdx.x;
  int per_g = 8 * ntn;
  int g = bid / per_g, ing = bid % per_g;
  int bm = g * 8 + (ing & 7), bn = ing >> 3;
  size_t m0 = (size_t)bm * 128, n0 = (size_t)bn * 128;
  int tid = threadIdx.x, wid = tid >> 6, lane = tid & 63;
  int wr = wid >> 1, wc = wid & 1, l15 = lane & 15, l4 = lane >> 4;
  int srow = lane >> 3, sch = lane & 7;

  f32x4 acc[4][4];
#pragma unroll
  for (int a = 0; a < 4; a++)
#pragma unroll
    for (int b2 = 0; b2 < 4; b2++) acc[a][b2] = f32x4{0.f, 0.f, 0.f, 0.f};

  int nk = K >> 6;
  for (int kt = 0; kt < nk; ++kt) {
    int k0 = kt << 6;
    __syncthreads();
    const u16* ga = A + (m0 + 32 * wid + srow) * K + k0 + sch * 8;
    const u16* gb = B + (n0 + 32 * wid + srow) * K + k0 + sch * 8;
#pragma unroll
    for (int c = 0; c < 4; c++) {
      gload_lds16(ga + (size_t)(8 * c) * K, &Alds[(32 * wid + 8 * c) * BK]);
      gload_lds16(gb + (size_t)(8 * c) * K, &Blds[(32 * wid + 8 * c) * BK]);
    }
    __syncthreads();
#pragma unroll
    for (int kk = 0; kk < 2; kk++) {
      bf16x8 af[4], bfr[4];
#pragma unroll
      for (int mi = 0; mi < 4; mi++)
        af[mi] = *(const bf16x8*)&Alds[(64 * wr + 16 * mi + l15) * BK + kk * 32 + 8 * l4];
#pragma unroll
      for (int ni = 0; ni < 4; ni++)
        bfr[ni] = *(const bf16x8*)&Blds[(64 * wc + 16 * ni + l15) * BK + kk * 32 + 8 * l4];
#pragma unroll
      for (int mi = 0; mi < 4; mi++)
#pragma unroll
        for (int ni = 0; ni < 4; ni++)
          acc[mi][ni] = mfma16(af[mi], bfr[ni], acc[mi][ni]);
    }
  }
#pragma unroll
  for (int mi = 0; mi < 4; mi++) {
#pragma unroll
    for (int ni = 0; ni < 4; ni++) {
      size_t row = m0 + 64 * wr + 16 * mi + 4 * l4;
      size_t col = n0 + 64 * wc + 16 * ni + l15;
#pragma unroll
      for (int i = 0; i < 4; i++) {
        float v = acc[mi][ni][i];
        if constexpr (OUTF32) {
          ((float*)C)[(row + i) * N + col] = v + bias[col];
        } else {
          ((u16*)C)[(row + i) * N + col] = f2bf(v);
        }
      }
    }
  }
}

// ---------------- transform: RMSNorm + RoPE + v-mix, layouts for attention ----------------
__global__ __launch_bounds__(256) void transform_kernel(
    const u16* __restrict__ qkv, const float* __restrict__ ve,
    const float* __restrict__ lam, const float* __restrict__ ct,
    const float* __restrict__ st, u16* __restrict__ qn, u16* __restrict__ kn,
    u16* __restrict__ vt) {
  constexpr int T = 2048, HD = 128;
  __shared__ u16 vtile[64][132];
  int tt = blockIdx.x, bh = blockIdx.y;
  int b = bh >> 3, h = bh & 7;
  int tid = threadIdx.x, wid = tid >> 6, lane = tid & 63;
  float l0 = lam[0], l1 = lam[1];
  int d0 = 2 * lane;
  float sgn = (lane < 32) ? -1.f : 1.f;
#pragma unroll 1
  for (int j = 0; j < 16; ++j) {
    int tl = wid * 16 + j;
    int t = tt * 64 + tl;
    size_t base = ((size_t)(b * T + t)) * 3072 + h * HD + d0;
    u16x2 qraw = *(const u16x2*)(qkv + base);
    u16x2 kraw = *(const u16x2*)(qkv + base + 1024);
    u16x2 vraw = *(const u16x2*)(qkv + base + 2048);
    f32x2 vef = *(const f32x2*)(ve + ((size_t)(b * T + t)) * 1024 + h * HD + d0);
    float q0 = bf2f(qraw[0]), q1 = bf2f(qraw[1]);
    float k0 = bf2f(kraw[0]), k1 = bf2f(kraw[1]);
    float sq = q0 * q0 + q1 * q1, sk = k0 * k0 + k1 * k1;
#pragma unroll
    for (int m = 1; m < 64; m <<= 1) {
      sq += __shfl_xor(sq, m);
      sk += __shfl_xor(sk, m);
    }
    float qs = rsqrtf(sq * (1.f / 128.f) + 1.1920929e-7f);
    float ks = rsqrtf(sk * (1.f / 128.f) + 1.1920929e-7f);
    q0 *= qs; q1 *= qs; k0 *= ks; k1 *= ks;
    int jj = d0 & 63;
    f32x2 c2 = *(const f32x2*)(ct + t * 64 + jj);
    f32x2 s2 = *(const f32x2*)(st + t * 64 + jj);
    float q0p = __shfl_xor(q0, 32), q1p = __shfl_xor(q1, 32);
    float k0p = __shfl_xor(k0, 32), k1p = __shfl_xor(k1, 32);
    u16x2 oq, ok;
    oq[0] = f2bf(q0 * c2[0] + sgn * q0p * s2[0]);
    oq[1] = f2bf(q1 * c2[1] + sgn * q1p * s2[1]);
    ok[0] = f2bf(k0 * c2[0] + sgn * k0p * s2[0]);
    ok[1] = f2bf(k1 * c2[1] + sgn * k1p * s2[1]);
    size_t orow = ((size_t)bh * T + t) * HD + d0;
    *(u16x2*)(qn + orow) = oq;
    *(u16x2*)(kn + orow) = ok;
    vtile[tl][d0] = f2bf(l0 * bf2f(vraw[0]) + l1 * vef[0]);
    vtile[tl][d0 + 1] = f2bf(l0 * bf2f(vraw[1]) + l1 * vef[1]);
  }
  __syncthreads();
  // write V transposed: vt[bh][d][t]
#pragma unroll
  for (int it = 0; it < 4; ++it) {
    int ci = it * 256 + tid;
    int d = ci >> 3, c8 = ci & 7;
    u16x8 o;
#pragma unroll
    for (int u = 0; u < 8; u++) o[u] = vtile[c8 * 8 + u][d];
    *(u16x8*)(vt + ((size_t)bh * HD + d) * T + tt * 64 + c8 * 8) = o;
  }
}

// ---------------- causal flash attention (swapped-QK^T, 32x32 MFMA, in-reg softmax) ----------------
// 512 blocks = (16 q-supertiles of 128 rows) x (32 bh), LPT descending-extent order.
// 4 waves/block, 32 q-rows/wave. K/V double-buffered in LDS via global_load_lds with
// pre-swizzled global source (linear LDS dest, XOR-swizzled content).
__global__ __launch_bounds__(256, 2) void attn_kernel(
    const u16* __restrict__ Qn, const u16* __restrict__ Kn,
    const u16* __restrict__ Vt, u16* __restrict__ Y) {
  constexpr int T = 2048;
  __shared__ u16 Klds[2][64 * 128];   // [kv 64][d 128], swizzled
  __shared__ u16 Vlds[2][128 * 64];   // [d 128][kv 64], swizzled
  int bid = blockIdx.x;
  int s = 15 - (bid >> 5);            // descending work for LPT scheduling
  int bh = bid & 31;
  int b = bh >> 3, h = bh & 7;
  int tid = threadIdx.x, wid = tid >> 6, lane = tid & 63;
  int l31 = lane & 31, hh = lane >> 5;
  const u16* Qb = Qn + (size_t)bh * T * 128;
  const u16* Kb = Kn + (size_t)bh * T * 128;
  const u16* Vb = Vt + (size_t)bh * 128 * T;
  int q0w = s * 128 + wid * 32;
  int qmaxw = q0w + 31;
  int ktend = 2 * s + 2;
  int qg = q0w + l31;

  // Q fragments: B-operand layout B[k=d][n=q]: q = l31, d = 16*ks + 8*hh + j
  bf16x8 qf[8];
  {
    const u16* qr = Qb + (size_t)(q0w + l31) * 128 + 8 * hh;
#pragma unroll
    for (int ks = 0; ks < 8; ks++) qf[ks] = *(const bf16x8*)(qr + 16 * ks);
  }
  f32x16 acc[4];
#pragma unroll
  for (int mt = 0; mt < 4; mt++)
#pragma unroll
    for (int r = 0; r < 16; r++) acc[mt][r] = 0.f;
  float m_run = -1e30f, l_run = 0.f;

  auto stage = [&](int buf, int kt) {
#pragma unroll
    for (int it = 0; it < 4; ++it) {
      int id = wid * 256 + it * 64 + lane;
      int r = id >> 4, c = id & 15;       // K: 64 rows x 16 chunks of 16B
      gload_lds16(Kb + (size_t)(kt * 64 + r) * 128 + 8 * (c ^ (r & 7)),
                  &Klds[buf][(size_t)(wid * 256 + it * 64) * 8]);
      int rv = id >> 3, cv = id & 7;      // V: 128 rows x 8 chunks of 16B
      gload_lds16(Vb + (size_t)rv * T + kt * 64 + 8 * (cv ^ (rv & 7)),
                  &Vlds[buf][(size_t)(wid * 256 + it * 64) * 8]);
    }
  };

  stage(0, 0);
  __syncthreads();

  for (int kt = 0; kt < ktend; ++kt) {
    int cur = kt & 1;
    if (kt + 1 < ktend) stage(cur ^ 1, kt + 1);
    if (kt * 64 <= qmaxw) {
      const char* kb = (const char*)&Klds[cur][0];
      const char* vb = (const char*)&Vlds[cur][0];
      int rswz = (l31 & 7) << 4;
      // S^T = K . Q^T : per-lane holds S[q=l31][kv] over 32 kv values
      f32x16 st0, st1;
#pragma unroll
      for (int r = 0; r < 16; r++) { st0[r] = 0.f; st1[r] = 0.f; }
#pragma unroll
      for (int ks = 0; ks < 8; ks++) {
        bf16x8 kf0 = *(const bf16x8*)(kb + ((l31 * 256 + 32 * ks + 16 * hh) ^ rswz));
        bf16x8 kf1 = *(const bf16x8*)(kb + (((32 + l31) * 256 + 32 * ks + 16 * hh) ^ rswz));
        st0 = mfma32(kf0, qf[ks], st0);
        st1 = mfma32(kf1, qf[ks], st1);
      }
      // scale + causal mask (edge tile only): kv(t,r) = kt*64 + 32t + (r&3) + 8*(r>>2) + 4*hh
      bool edge = (kt == (qmaxw >> 6));
      if (edge) {
#pragma unroll
        for (int r = 0; r < 16; r++) {
          int kvb = kt * 64 + (r & 3) + 8 * (r >> 2) + 4 * hh;
          st0[r] = (kvb > qg) ? -1e30f : st0[r] * 0.12f;
          st1[r] = (kvb + 32 > qg) ? -1e30f : st1[r] * 0.12f;
        }
      } else {
#pragma unroll
        for (int r = 0; r < 16; r++) { st0[r] *= 0.12f; st1[r] *= 0.12f; }
      }
      // in-lane max tree + pair combine
      float m8[8];
#pragma unroll
      for (int r = 0; r < 8; r++)
        m8[r] = fmaxf(fmaxf(st0[r], st0[r + 8]), fmaxf(st1[r], st1[r + 8]));
#pragma unroll
      for (int r = 0; r < 4; r++) m8[r] = fmaxf(m8[r], m8[r + 4]);
      float pm = fmaxf(fmaxf(m8[0], m8[1]), fmaxf(m8[2], m8[3]));
      pm = fmaxf(pm, __shfl_xor(pm, 32));
      float mnew = fmaxf(m_run, pm);
      float alpha = __expf(m_run - mnew);
      m_run = mnew;
      float sa = 0.f, sb = 0.f, sc = 0.f, sd = 0.f;
#pragma unroll
      for (int r = 0; r < 4; r++) {
        st0[r]      = __expf(st0[r]      - mnew); sa += st0[r];
        st0[r + 4]  = __expf(st0[r + 4]  - mnew); sb += st0[r + 4];
        st0[r + 8]  = __expf(st0[r + 8]  - mnew); sc += st0[r + 8];
        st0[r + 12] = __expf(st0[r + 12] - mnew); sd += st0[r + 12];
        st1[r]      = __expf(st1[r]      - mnew); sa += st1[r];
        st1[r + 4]  = __expf(st1[r + 4]  - mnew); sb += st1[r + 4];
        st1[r + 8]  = __expf(st1[r + 8]  - mnew); sc += st1[r + 8];
        st1[r + 12] = __expf(st1[r + 12] - mnew); sd += st1[r + 12];
      }
      float ps = (sa + sb) + (sc + sd);
      ps += __shfl_xor(ps, 32);
      l_run = l_run * alpha + ps;
#pragma unroll
      for (int mt = 0; mt < 4; mt++)
#pragma unroll
        for (int r = 0; r < 16; r++) acc[mt][r] *= alpha;
      // pack P to bf16 and build PV B-frags via permlane32_swap
      unsigned pA0[4], pB0[4], pA1[4], pB1[4];
#pragma unroll
      for (int rr = 0; rr < 4; rr++) {
        pA0[rr] = cvtpk_bf16(st0[4 * rr], st0[4 * rr + 1]);
        pB0[rr] = cvtpk_bf16(st0[4 * rr + 2], st0[4 * rr + 3]);
        pA1[rr] = cvtpk_bf16(st1[4 * rr], st1[4 * rr + 1]);
        pB1[rr] = cvtpk_bf16(st1[4 * rr + 2], st1[4 * rr + 3]);
      }
      bf16x8 pf[4];
#pragma unroll
      for (int ks2 = 0; ks2 < 4; ks2++) {
        int k1 = ks2 & 1;
        unsigned a0, b0, a1, b1;
        if (ks2 < 2) { a0 = pA0[2 * k1]; b0 = pA0[2 * k1 + 1]; a1 = pB0[2 * k1]; b1 = pB0[2 * k1 + 1]; }
        else         { a0 = pA1[2 * k1]; b0 = pA1[2 * k1 + 1]; a1 = pB1[2 * k1]; b1 = pB1[2 * k1 + 1]; }
        pswap32(a0, b0);   // a0 = word0 (j0,j1), b0 = word2 (j4,j5)
        pswap32(a1, b1);   // a1 = word1 (j2,j3), b1 = word3 (j6,j7)
        union { unsigned w[4]; bf16x8 v; } u;
        u.w[0] = a0; u.w[1] = a1; u.w[2] = b0; u.w[3] = b1;
        pf[ks2] = u.v;
      }
      // O^T += V^T . P^T
#pragma unroll
      for (int mt = 0; mt < 4; mt++) {
        int row = 32 * mt + l31;
#pragma unroll
        for (int ks2 = 0; ks2 < 4; ks2++) {
          bf16x8 vf = *(const bf16x8*)(vb + ((row * 128 + 32 * ks2 + 16 * hh) ^ rswz));
          acc[mt] = mfma32(vf, pf[ks2], acc[mt]);
        }
      }
    }
    __syncthreads();
  }
  // epilogue: O^T reg (d = 32mt + 8rr + 4hh + i, q = l31) -> Y[b*T+q][h*128+d]
  float linv = 1.f / l_run;
  size_t yrow = (size_t)b * T + q0w + l31;
  u16* yp = Y + yrow * 1024 + h * 128;
#pragma unroll
  for (int mt = 0; mt < 4; mt++) {
#pragma unroll
    for (int rr = 0; rr < 4; rr++) {
      u16x4 o;
#pragma unroll
      for (int i = 0; i < 4; i++) o[i] = f2bf(acc[mt][4 * rr + i] * linv);
      *(u16x4*)(yp + 32 * mt + 8 * rr + 4 * hh) = o;
    }
  }
}

// ---------------- launch ----------------
extern "C" void kernel_launch(void* const* d_in, const int* in_sizes, int n_in,
                              void* d_out, int out_size, void* d_ws, size_t ws_size,
                              hipStream_t stream) {
  (void)in_sizes; (void)n_in; (void)out_size; (void)ws_size;
  const float* x = (const float*)d_in[0];
  const float* ve = (const float*)d_in[1];
  const float* qkvw = (const float*)d_in[2];
  const float* lam = (const float*)d_in[3];
  const float* cpw = (const float*)d_in[4];
  const float* cpb = (const float*)d_in[5];
  float* out = (float*)d_out;
  char* ws = (char*)d_ws;

  u16* xb   = (u16*)(ws + 0);           // 16 MB  (aliased by y after GEMM1)
  u16* wqkv = (u16*)(ws + 16777216);    // 6 MB
  u16* wp   = (u16*)(ws + 23068672);    // 2 MB
  u16* qkv  = (u16*)(ws + 25165824);    // 48 MB
  u16* qn   = (u16*)(ws + 75497472);    // 16 MB
  u16* kn   = (u16*)(ws + 92274688);    // 16 MB
  u16* vt   = (u16*)(ws + 109051904);   // 16 MB
  float* ctab = (float*)(ws + 125829120);  // 0.5 MB
  float* stab = (float*)(ws + 126353408);  // 0.5 MB
  u16* y = xb;                          // alias: xb dead after GEMM1

  rope_tab_kernel<<<512, 256, 0, stream>>>(ctab, stab);
  cvt_bf16_kernel<<<8192, 256, 0, stream>>>(x, xb, 2097152);
  cvt_bf16_kernel<<<3072, 256, 0, stream>>>(qkvw, wqkv, 786432);
  cvt_bf16_kernel<<<1024, 256, 0, stream>>>(cpw, wp, 262144);
  gemm_bt_kernel<0><<<1536, 256, 0, stream>>>(xb, wqkv, qkv, nullptr, 8192, 3072, 1024, 24);
  transform_kernel<<<dim3(32, 32), 256, 0, stream>>>(qkv, ve, lam, ctab, stab, qn, kn, vt);
  attn_kernel<<<512, 256, 0, stream>>>(qn, kn, vt, y);
  gemm_bt_kernel<1><<<512, 256, 0, stream>>>(y, wp, out, cpb, 8192, 1024, 1024, 8);
}

// Round 3
// 209.773 us; speedup vs baseline: 1.5952x; 1.0807x over previous
//
#include <hip/hip_runtime.h>
#include <math.h>

typedef unsigned short u16;
typedef short bf16x8 __attribute__((ext_vector_type(8)));
typedef u16 u16x2 __attribute__((ext_vector_type(2)));
typedef u16 u16x4 __attribute__((ext_vector_type(4)));
typedef u16 u16x8 __attribute__((ext_vector_type(8)));
typedef float f32x2 __attribute__((ext_vector_type(2)));
typedef float f32x4 __attribute__((ext_vector_type(4)));
typedef float f32x16 __attribute__((ext_vector_type(16)));

typedef __attribute__((address_space(1))) const void gvoid_t;
typedef __attribute__((address_space(3))) void lvoid_t;

__device__ __forceinline__ u16 f2bf(float f) {
  union { float f; unsigned u; } v; v.f = f;
  unsigned r = v.u + 0x7fffu + ((v.u >> 16) & 1u);
  return (u16)(r >> 16);
}
__device__ __forceinline__ float bf2f(u16 h) {
  union { unsigned u; float f; } v; v.u = ((unsigned)h) << 16;
  return v.f;
}
__device__ __forceinline__ f32x4 mfma16(bf16x8 a, bf16x8 b, f32x4 c) {
  return __builtin_amdgcn_mfma_f32_16x16x32_bf16(a, b, c, 0, 0, 0);
}
__device__ __forceinline__ f32x16 mfma32(bf16x8 a, bf16x8 b, f32x16 c) {
  return __builtin_amdgcn_mfma_f32_32x32x16_bf16(a, b, c, 0, 0, 0);
}
__device__ __forceinline__ void gload_lds16(const void* g, void* l) {
  __builtin_amdgcn_global_load_lds((gvoid_t*)g, (lvoid_t*)l, 16, 0, 0);
}
__device__ __forceinline__ unsigned cvtpk_bf16(float lo, float hi) {
  unsigned r;
  asm("v_cvt_pk_bf16_f32 %0, %1, %2" : "=v"(r) : "v"(lo), "v"(hi));
  return r;
}
__device__ __forceinline__ void pswap32(unsigned& a, unsigned& b) {
  asm("v_permlane32_swap_b32 %0, %1" : "+v"(a), "+v"(b));
}

#define BAR() __builtin_amdgcn_s_barrier()
#define WAITLGKM()                          \
  asm volatile("s_waitcnt lgkmcnt(0)");     \
  __builtin_amdgcn_sched_barrier(0)
#define WAITVM2()                           \
  asm volatile("s_waitcnt vmcnt(2)");       \
  __builtin_amdgcn_sched_barrier(0)
#define WAITVM4()                           \
  asm volatile("s_waitcnt vmcnt(4)");       \
  __builtin_amdgcn_sched_barrier(0)

// ---------------- fp32 -> bf16 conversion ----------------
__global__ __launch_bounds__(256) void cvt_bf16_kernel(const float* __restrict__ in,
                                                       u16* __restrict__ out, int n4) {
  int i = blockIdx.x * 256 + threadIdx.x;
  if (i >= n4) return;
  f32x4 v = *(const f32x4*)(in + (size_t)i * 4);
  u16x4 o;
  o[0] = f2bf(v[0]); o[1] = f2bf(v[1]); o[2] = f2bf(v[2]); o[3] = f2bf(v[3]);
  *(u16x4*)(out + (size_t)i * 4) = o;
}

// ---------------- RoPE cos/sin tables [T][64] ----------------
__global__ __launch_bounds__(256) void rope_tab_kernel(float* __restrict__ ct,
                                                       float* __restrict__ st) {
  int i = blockIdx.x * 256 + threadIdx.x;
  int t = i >> 6, j = i & 63;
  float inv = powf(10000.f, -(float)j * (1.0f / 64.0f));
  float ang = (float)t * inv;
  ct[i] = cosf(ang);
  st[i] = sinf(ang);
}

// ---------------- 256x256 8-phase GEMM: C[M,N] = A[M,K] * B[N,K]^T ----------------
// m201 template: BK=64, 8 waves (2Mx4N), per-wave 128x64, double-buffered swizzled LDS,
// counted vmcnt (never 0), raw s_barrier, setprio around MFMA clusters.
template <int OUTF32>
__global__ __launch_bounds__(512, 2) void gemm8p_kernel(
    const u16* __restrict__ A, const u16* __restrict__ B, void* __restrict__ C,
    const float* __restrict__ bias, int M, int N, int K, int nbn) {
  __shared__ u16 Alds[2][256 * 64];
  __shared__ u16 Blds[2][256 * 64];
  int nwg = gridDim.x;
  int cpx = nwg >> 3;
  int bid = blockIdx.x;
  int swz = (bid & 7) * cpx + (bid >> 3);   // bijective XCD swizzle (nwg % 8 == 0)
  int bm = swz / nbn, bn = swz % nbn;
  size_t m0 = (size_t)bm * 256, n0 = (size_t)bn * 256;
  int tid = threadIdx.x, wid = tid >> 6, lane = tid & 63;
  int wr = wid >> 2, wc = wid & 3, l15 = lane & 15, l4 = lane >> 4;
  int srow = tid >> 3, sch = tid & 7;      // staging coords: 64 rows x 8 chunks/round

  const u16* Abase = A + m0 * K;
  const u16* Bbase = B + n0 * K;

  f32x4 acc[8][4];
#pragma unroll
  for (int m = 0; m < 8; m++)
#pragma unroll
    for (int n = 0; n < 4; n++) acc[m][n] = f32x4{0.f, 0.f, 0.f, 0.f};

  // stage one 128-row half-tile (2 gload rounds of 64 rows) with inverse-swizzled source
  auto stageA = [&](int buf, int kt, int half) {
#pragma unroll
    for (int r = 0; r < 2; ++r) {
      int row = 128 * half + 64 * r + srow;
      gload_lds16(Abase + (size_t)row * K + kt * 64 + 8 * (sch ^ (row & 7)),
                  &Alds[buf][(128 * half + 64 * r + 8 * wid) * 64]);
    }
  };
  auto stageB = [&](int buf, int kt, int half) {
#pragma unroll
    for (int r = 0; r < 2; ++r) {
      int row = 128 * half + 64 * r + srow;
      gload_lds16(Bbase + (size_t)row * K + kt * 64 + 8 * (sch ^ (row & 7)),
                  &Blds[buf][(128 * half + 64 * r + 8 * wid) * 64]);
    }
  };
  auto rdA = [&](int buf, int half, bf16x8 (&a)[4][2]) {
#pragma unroll
    for (int mi = 0; mi < 4; ++mi)
#pragma unroll
      for (int kk = 0; kk < 2; ++kk) {
        int row = 128 * wr + 64 * half + 16 * mi + l15;
        a[mi][kk] = *(const bf16x8*)((const char*)(&Alds[buf][0]) + row * 128 +
                                     ((kk * 64 + 16 * l4) ^ ((row & 7) << 4)));
      }
  };
  auto rdB = [&](int buf, int half, bf16x8 (&bb)[2][2]) {
#pragma unroll
    for (int ni = 0; ni < 2; ++ni)
#pragma unroll
      for (int kk = 0; kk < 2; ++kk) {
        int row = 64 * wc + 32 * half + 16 * ni + l15;
        bb[ni][kk] = *(const bf16x8*)((const char*)(&Blds[buf][0]) + row * 128 +
                                      ((kk * 64 + 16 * l4) ^ ((row & 7) << 4)));
      }
  };

#define QUAD(AF, BF, MH, NH)                                              \
  do {                                                                    \
    __builtin_amdgcn_s_setprio(1);                                        \
    _Pragma("unroll") for (int mi = 0; mi < 4; ++mi)                      \
        _Pragma("unroll") for (int ni = 0; ni < 2; ++ni)                  \
            _Pragma("unroll") for (int kk = 0; kk < 2; ++kk)              \
                acc[4 * MH + mi][2 * NH + ni] =                           \
        mfma16(AF[mi][kk], BF[ni][kk], acc[4 * MH + mi][2 * NH + ni]);    \
    __builtin_amdgcn_s_setprio(0);                                        \
  } while (0)

  // prologue: stage tile 0 (order B0,B1,A0,A1), allow newest half-tile in flight
  stageB(0, 0, 0);
  stageB(0, 0, 1);
  stageA(0, 0, 0);
  stageA(0, 0, 1);
  WAITVM2();
  BAR();

  int nk = K >> 6;
  bf16x8 a0[4][2], a1[4][2], b0[2][2], b1[2][2];
  for (int t = 0; t < nk; ++t) {
    int buf = t & 1, nxt = buf ^ 1;
    bool pf = (t + 1 < nk);
    // P0: A-half0 + B-half0 reads; stage next B0; compute Q00
    rdA(buf, 0, a0);
    rdB(buf, 0, b0);
    if (pf) stageB(nxt, t + 1, 0);
    BAR();
    WAITLGKM();
    QUAD(a0, b0, 0, 0);
    BAR();
    // P1: B-half1 reads; stage next B1; compute Q01
    rdB(buf, 1, b1);
    if (pf) stageB(nxt, t + 1, 1);
    BAR();
    WAITLGKM();
    QUAD(a0, b1, 0, 1);
    WAITVM4();        // ensures this tile's A1 has landed (across barrier)
    BAR();
    // P2: A-half1 reads; stage next A0; compute Q10
    rdA(buf, 1, a1);
    if (pf) stageA(nxt, t + 1, 0);
    BAR();
    WAITLGKM();
    QUAD(a1, b0, 1, 0);
    BAR();
    // P3: stage next A1; compute Q11
    if (pf) stageA(nxt, t + 1, 1);
    BAR();
    QUAD(a1, b1, 1, 1);
    WAITVM2();        // next tile's B0,B1,A0 landed; its A1 may stay in flight
    BAR();
  }

#pragma unroll
  for (int mi = 0; mi < 8; ++mi) {
#pragma unroll
    for (int ni = 0; ni < 4; ++ni) {
      size_t row = m0 + 128 * wr + 16 * mi + 4 * l4;
      size_t col = n0 + 64 * wc + 16 * ni + l15;
#pragma unroll
      for (int i = 0; i < 4; ++i) {
        float v = acc[mi][ni][i];
        if constexpr (OUTF32) {
          ((float*)C)[(row + i) * N + col] = v + bias[col];
        } else {
          ((u16*)C)[(row + i) * N + col] = f2bf(v);
        }
      }
    }
  }
#undef QUAD
}

// ---------------- transform: RMSNorm + RoPE + v-mix, layouts for attention ----------------
__global__ __launch_bounds__(256) void transform_kernel(
    const u16* __restrict__ qkv, const float* __restrict__ ve,
    const float* __restrict__ lam, const float* __restrict__ ct,
    const float* __restrict__ st, u16* __restrict__ qn, u16* __restrict__ kn,
    u16* __restrict__ vt) {
  constexpr int T = 2048, HD = 128;
  __shared__ u16 vtile[64][132];
  int tt = blockIdx.x, bh = blockIdx.y;
  int b = bh >> 3, h = bh & 7;
  int tid = threadIdx.x, wid = tid >> 6, lane = tid & 63;
  float l0 = lam[0], l1 = lam[1];
  int d0 = 2 * lane;
  float sgn = (lane < 32) ? -1.f : 1.f;
#pragma unroll 1
  for (int j = 0; j < 16; ++j) {
    int tl = wid * 16 + j;
    int t = tt * 64 + tl;
    size_t base = ((size_t)(b * T + t)) * 3072 + h * HD + d0;
    u16x2 qraw = *(const u16x2*)(qkv + base);
    u16x2 kraw = *(const u16x2*)(qkv + base + 1024);
    u16x2 vraw = *(const u16x2*)(qkv + base + 2048);
    f32x2 vef = *(const f32x2*)(ve + ((size_t)(b * T + t)) * 1024 + h * HD + d0);
    float q0 = bf2f(qraw[0]), q1 = bf2f(qraw[1]);
    float k0 = bf2f(kraw[0]), k1 = bf2f(kraw[1]);
    float sq = q0 * q0 + q1 * q1, sk = k0 * k0 + k1 * k1;
#pragma unroll
    for (int m = 1; m < 64; m <<= 1) {
      sq += __shfl_xor(sq, m);
      sk += __shfl_xor(sk, m);
    }
    float qs = rsqrtf(sq * (1.f / 128.f) + 1.1920929e-7f);
    float ks = rsqrtf(sk * (1.f / 128.f) + 1.1920929e-7f);
    q0 *= qs; q1 *= qs; k0 *= ks; k1 *= ks;
    int jj = d0 & 63;
    f32x2 c2 = *(const f32x2*)(ct + t * 64 + jj);
    f32x2 s2 = *(const f32x2*)(st + t * 64 + jj);
    float q0p = __shfl_xor(q0, 32), q1p = __shfl_xor(q1, 32);
    float k0p = __shfl_xor(k0, 32), k1p = __shfl_xor(k1, 32);
    u16x2 oq, ok;
    oq[0] = f2bf(q0 * c2[0] + sgn * q0p * s2[0]);
    oq[1] = f2bf(q1 * c2[1] + sgn * q1p * s2[1]);
    ok[0] = f2bf(k0 * c2[0] + sgn * k0p * s2[0]);
    ok[1] = f2bf(k1 * c2[1] + sgn * k1p * s2[1]);
    size_t orow = ((size_t)bh * T + t) * HD + d0;
    *(u16x2*)(qn + orow) = oq;
    *(u16x2*)(kn + orow) = ok;
    vtile[tl][d0] = f2bf(l0 * bf2f(vraw[0]) + l1 * vef[0]);
    vtile[tl][d0 + 1] = f2bf(l0 * bf2f(vraw[1]) + l1 * vef[1]);
  }
  __syncthreads();
#pragma unroll
  for (int it = 0; it < 4; ++it) {
    int ci = it * 256 + tid;
    int d = ci >> 3, c8 = ci & 7;
    u16x8 o;
#pragma unroll
    for (int u = 0; u < 8; u++) o[u] = vtile[c8 * 8 + u][d];
    *(u16x8*)(vt + ((size_t)bh * HD + d) * T + tt * 64 + c8 * 8) = o;
  }
}

// ---------------- causal flash attention (swapped-QK^T, 32x32 MFMA, in-reg softmax) ----------------
__global__ __launch_bounds__(256, 2) void attn_kernel(
    const u16* __restrict__ Qn, const u16* __restrict__ Kn,
    const u16* __restrict__ Vt, u16* __restrict__ Y) {
  constexpr int T = 2048;
  __shared__ u16 Klds[2][64 * 128];
  __shared__ u16 Vlds[2][128 * 64];
  int bid = blockIdx.x;
  int s = 15 - (bid >> 5);
  int bh = bid & 31;
  int b = bh >> 3, h = bh & 7;
  int tid = threadIdx.x, wid = tid >> 6, lane = tid & 63;
  int l31 = lane & 31, hh = lane >> 5;
  const u16* Qb = Qn + (size_t)bh * T * 128;
  const u16* Kb = Kn + (size_t)bh * T * 128;
  const u16* Vb = Vt + (size_t)bh * 128 * T;
  int q0w = s * 128 + wid * 32;
  int qmaxw = q0w + 31;
  int ktend = 2 * s + 2;
  int qg = q0w + l31;

  bf16x8 qf[8];
  {
    const u16* qr = Qb + (size_t)(q0w + l31) * 128 + 8 * hh;
#pragma unroll
    for (int ks = 0; ks < 8; ks++) qf[ks] = *(const bf16x8*)(qr + 16 * ks);
  }
  f32x16 acc[4];
#pragma unroll
  for (int mt = 0; mt < 4; mt++)
#pragma unroll
    for (int r = 0; r < 16; r++) acc[mt][r] = 0.f;
  float m_run = -1e30f, l_run = 0.f;

  auto stage = [&](int buf, int kt) {
#pragma unroll
    for (int it = 0; it < 4; ++it) {
      int id = wid * 256 + it * 64 + lane;
      int r = id >> 4, c = id & 15;
      gload_lds16(Kb + (size_t)(kt * 64 + r) * 128 + 8 * (c ^ (r & 7)),
                  &Klds[buf][(size_t)(wid * 256 + it * 64) * 8]);
      int rv = id >> 3, cv = id & 7;
      gload_lds16(Vb + (size_t)rv * T + kt * 64 + 8 * (cv ^ (rv & 7)),
                  &Vlds[buf][(size_t)(wid * 256 + it * 64) * 8]);
    }
  };

  stage(0, 0);
  __syncthreads();

  for (int kt = 0; kt < ktend; ++kt) {
    int cur = kt & 1;
    if (kt + 1 < ktend) stage(cur ^ 1, kt + 1);
    if (kt * 64 <= qmaxw) {
      const char* kb = (const char*)&Klds[cur][0];
      const char* vb = (const char*)&Vlds[cur][0];
      int rswz = (l31 & 7) << 4;
      f32x16 st0, st1;
#pragma unroll
      for (int r = 0; r < 16; r++) { st0[r] = 0.f; st1[r] = 0.f; }
#pragma unroll
      for (int ks = 0; ks < 8; ks++) {
        bf16x8 kf0 = *(const bf16x8*)(kb + ((l31 * 256 + 32 * ks + 16 * hh) ^ rswz));
        bf16x8 kf1 = *(const bf16x8*)(kb + (((32 + l31) * 256 + 32 * ks + 16 * hh) ^ rswz));
        st0 = mfma32(kf0, qf[ks], st0);
        st1 = mfma32(kf1, qf[ks], st1);
      }
      bool edge = (kt == (qmaxw >> 6));
      if (edge) {
#pragma unroll
        for (int r = 0; r < 16; r++) {
          int kvb = kt * 64 + (r & 3) + 8 * (r >> 2) + 4 * hh;
          st0[r] = (kvb > qg) ? -1e30f : st0[r] * 0.12f;
          st1[r] = (kvb + 32 > qg) ? -1e30f : st1[r] * 0.12f;
        }
      } else {
#pragma unroll
        for (int r = 0; r < 16; r++) { st0[r] *= 0.12f; st1[r] *= 0.12f; }
      }
      float m8[8];
#pragma unroll
      for (int r = 0; r < 8; r++)
        m8[r] = fmaxf(fmaxf(st0[r], st0[r + 8]), fmaxf(st1[r], st1[r + 8]));
#pragma unroll
      for (int r = 0; r < 4; r++) m8[r] = fmaxf(m8[r], m8[r + 4]);
      float pm = fmaxf(fmaxf(m8[0], m8[1]), fmaxf(m8[2], m8[3]));
      pm = fmaxf(pm, __shfl_xor(pm, 32));
      float mnew = fmaxf(m_run, pm);
      float alpha = __expf(m_run - mnew);
      m_run = mnew;
      float sa = 0.f, sb = 0.f, sc = 0.f, sd = 0.f;
#pragma unroll
      for (int r = 0; r < 4; r++) {
        st0[r]      = __expf(st0[r]      - mnew); sa += st0[r];
        st0[r + 4]  = __expf(st0[r + 4]  - mnew); sb += st0[r + 4];
        st0[r + 8]  = __expf(st0[r + 8]  - mnew); sc += st0[r + 8];
        st0[r + 12] = __expf(st0[r + 12] - mnew); sd += st0[r + 12];
        st1[r]      = __expf(st1[r]      - mnew); sa += st1[r];
        st1[r + 4]  = __expf(st1[r + 4]  - mnew); sb += st1[r + 4];
        st1[r + 8]  = __expf(st1[r + 8]  - mnew); sc += st1[r + 8];
        st1[r + 12] = __expf(st1[r + 12] - mnew); sd += st1[r + 12];
      }
      float ps = (sa + sb) + (sc + sd);
      ps += __shfl_xor(ps, 32);
      l_run = l_run * alpha + ps;
#pragma unroll
      for (int mt = 0; mt < 4; mt++)
#pragma unroll
        for (int r = 0; r < 16; r++) acc[mt][r] *= alpha;
      unsigned pA0[4], pB0[4], pA1[4], pB1[4];
#pragma unroll
      for (int rr = 0; rr < 4; rr++) {
        pA0[rr] = cvtpk_bf16(st0[4 * rr], st0[4 * rr + 1]);
        pB0[rr] = cvtpk_bf16(st0[4 * rr + 2], st0[4 * rr + 3]);
        pA1[rr] = cvtpk_bf16(st1[4 * rr], st1[4 * rr + 1]);
        pB1[rr] = cvtpk_bf16(st1[4 * rr + 2], st1[4 * rr + 3]);
      }
      bf16x8 pf[4];
#pragma unroll
      for (int ks2 = 0; ks2 < 4; ks2++) {
        int k1 = ks2 & 1;
        unsigned a0, b0, a1, b1;
        if (ks2 < 2) { a0 = pA0[2 * k1]; b0 = pA0[2 * k1 + 1]; a1 = pB0[2 * k1]; b1 = pB0[2 * k1 + 1]; }
        else         { a0 = pA1[2 * k1]; b0 = pA1[2 * k1 + 1]; a1 = pB1[2 * k1]; b1 = pB1[2 * k1 + 1]; }
        pswap32(a0, b0);
        pswap32(a1, b1);
        union { unsigned w[4]; bf16x8 v; } u;
        u.w[0] = a0; u.w[1] = a1; u.w[2] = b0; u.w[3] = b1;
        pf[ks2] = u.v;
      }
#pragma unroll
      for (int mt = 0; mt < 4; mt++) {
        int row = 32 * mt + l31;
#pragma unroll
        for (int ks2 = 0; ks2 < 4; ks2++) {
          bf16x8 vf = *(const bf16x8*)(vb + ((row * 128 + 32 * ks2 + 16 * hh) ^ rswz));
          acc[mt] = mfma32(vf, pf[ks2], acc[mt]);
        }
      }
    }
    __syncthreads();
  }
  float linv = 1.f / l_run;
  size_t yrow = (size_t)b * T + q0w + l31;
  u16* yp = Y + yrow * 1024 + h * 128;
#pragma unroll
  for (int mt = 0; mt < 4; mt++) {
#pragma unroll
    for (int rr = 0; rr < 4; rr++) {
      u16x4 o;
#pragma unroll
      for (int i = 0; i < 4; i++) o[i] = f2bf(acc[mt][4 * rr + i] * linv);
      *(u16x4*)(yp + 32 * mt + 8 * rr + 4 * hh) = o;
    }
  }
}

// ---------------- launch ----------------
extern "C" void kernel_launch(void* const* d_in, const int* in_sizes, int n_in,
                              void* d_out, int out_size, void* d_ws, size_t ws_size,
                              hipStream_t stream) {
  (void)in_sizes; (void)n_in; (void)out_size; (void)ws_size;
  const float* x = (const float*)d_in[0];
  const float* ve = (const float*)d_in[1];
  const float* qkvw = (const float*)d_in[2];
  const float* lam = (const float*)d_in[3];
  const float* cpw = (const float*)d_in[4];
  const float* cpb = (const float*)d_in[5];
  float* out = (float*)d_out;
  char* ws = (char*)d_ws;

  u16* xb   = (u16*)(ws + 0);           // 16 MB  (aliased by y after GEMM1)
  u16* wqkv = (u16*)(ws + 16777216);    // 6 MB
  u16* wp   = (u16*)(ws + 23068672);    // 2 MB
  u16* qkv  = (u16*)(ws + 25165824);    // 48 MB
  u16* qn   = (u16*)(ws + 75497472);    // 16 MB
  u16* kn   = (u16*)(ws + 92274688);    // 16 MB
  u16* vt   = (u16*)(ws + 109051904);   // 16 MB
  float* ctab = (float*)(ws + 125829120);  // 0.5 MB
  float* stab = (float*)(ws + 126353408);  // 0.5 MB
  u16* y = xb;                          // alias: xb dead after GEMM1

  rope_tab_kernel<<<512, 256, 0, stream>>>(ctab, stab);
  cvt_bf16_kernel<<<8192, 256, 0, stream>>>(x, xb, 2097152);
  cvt_bf16_kernel<<<3072, 256, 0, stream>>>(qkvw, wqkv, 786432);
  cvt_bf16_kernel<<<1024, 256, 0, stream>>>(cpw, wp, 262144);
  gemm8p_kernel<0><<<384, 512, 0, stream>>>(xb, wqkv, qkv, nullptr, 8192, 3072, 1024, 12);
  transform_kernel<<<dim3(32, 32), 256, 0, stream>>>(qkv, ve, lam, ctab, stab, qn, kn, vt);
  attn_kernel<<<512, 256, 0, stream>>>(qn, kn, vt, y);
  gemm8p_kernel<1><<<128, 512, 0, stream>>>(y, wp, out, cpb, 8192, 1024, 1024, 4);
}